// Round 8
// baseline (876.750 us; speedup 1.0000x reference)
//
#include <hip/hip_runtime.h>
#include <cmath>

// MLPTexture3D: 16-level hashgrid encode + 32->32->32->4 MLP.
// R7: counting sort, 32^3 Morton cells (R5's encode locality), single-pass
// rank: hist pass packs (cell,rank) per point via dual-u16 LDS counters
// (64 KB LDS, atomicAdd(1<<16*(c&1)) returns rank); scatter is full-grid,
// LDS-free: pos = hist[c*64+b] + rank. Scan over 2M-entry matrix = 5 tiny
// kernels. cr/hist/sums alias the enc region (binning finishes before encode).

namespace {
constexpr int kLevels = 16;
constexpr unsigned kTableSize = 1u << 19;
constexpr unsigned kMask = kTableSize - 1u;
constexpr int kNumCells = 1 << 15;       // 32^3 Morton cells
constexpr int kHistBlocks = 64;          // fat blocks for hist pass
constexpr int kHistEntries = kNumCells * kHistBlocks;  // 2M
constexpr int kScan1Blocks = kHistEntries / 256;       // 8192
constexpr int kScan2Blocks = kScan1Blocks / 256;       // 32

typedef _Float16 half2_t __attribute__((ext_vector_type(2)));
typedef unsigned int u32;

struct LevelParams {
  float scale[kLevels];
  unsigned res[kLevels];
  int dense[kLevels];
};
}  // namespace

__device__ __forceinline__ u32 part1by2(u32 x) {
  x &= 0x3FFu;
  x = (x | (x << 16)) & 0x030000FFu;
  x = (x | (x << 8))  & 0x0300F00Fu;
  x = (x | (x << 4))  & 0x030C30C3u;
  x = (x | (x << 2))  & 0x09249249u;
  return x;
}

__device__ __forceinline__ u32 cell_of(float x, float y, float z) {
  u32 cx = min((u32)(x * 32.f), 31u);
  u32 cy = min((u32)(y * 32.f), 31u);
  u32 cz = min((u32)(z * 32.f), 31u);
  return part1by2(cx) | (part1by2(cy) << 1) | (part1by2(cz) << 2);
}

// ---------------- k0: table conversion + weight packing ----------------
__global__ __launch_bounds__(256)
void conv_tables_kernel(const float2* __restrict__ src, half2_t* __restrict__ dst,
                        int n_entries,
                        const float* __restrict__ W1, const float* __restrict__ W2,
                        const float* __restrict__ W3, half2_t* __restrict__ Wh)
{
  int i = blockIdx.x * blockDim.x + threadIdx.x;
  if (i < 512) {
    Wh[i] = half2_t{(_Float16)W1[2 * i], (_Float16)W1[2 * i + 1]};
  } else if (i < 1024) {
    int t = i - 512;
    Wh[512 + t] = half2_t{(_Float16)W2[2 * t], (_Float16)W2[2 * t + 1]};
  } else if (i < 1088) {
    int t = i - 1024;
    Wh[1024 + t] = half2_t{(_Float16)W3[2 * t], (_Float16)W3[2 * t + 1]};
  }
  int stride = gridDim.x * blockDim.x;
  for (; i < n_entries; i += stride) {
    float2 v = src[i];
    dst[i] = half2_t{(_Float16)v.x, (_Float16)v.y};
  }
}

// ---------------- A: hist + per-point rank in one pass ----------------
// LDS: 32768 cells as dual u16 counters packed in 16384 u32 (64 KB).
__global__ __launch_bounds__(256)
void hist_pack_kernel(const float* __restrict__ points, const float* __restrict__ aabb,
                      u32* __restrict__ hist, u32* __restrict__ cr, int n, int ppb)
{
  __shared__ u32 h[kNumCells / 2];
  int t = threadIdx.x;
  int b = blockIdx.x;
  #pragma unroll
  for (int j = t; j < kNumCells / 2; j += 256) h[j] = 0u;
  __syncthreads();

  float a0x = aabb[0], a0y = aabb[1], a0z = aabb[2];
  float a1x = aabb[3], a1y = aabb[4], a1z = aabb[5];
  int start = b * ppb;
  int end = min(start + ppb, n);
  for (int i = start + t; i < end; i += 256) {
    float x = fminf(fmaxf((points[3 * i + 0] - a0x) / (a1x - a0x), 0.f), 1.f);
    float y = fminf(fmaxf((points[3 * i + 1] - a0y) / (a1y - a0y), 0.f), 1.f);
    float z = fminf(fmaxf((points[3 * i + 2] - a0z) / (a1z - a0z), 0.f), 1.f);
    u32 c = cell_of(x, y, z);
    u32 sh = (c & 1u) * 16u;
    u32 old = atomicAdd(&h[c >> 1], 1u << sh);
    u32 rank = (old >> sh) & 0xFFFFu;
    cr[i] = c | (rank << 15);         // cell 15 bits | rank (ppb<=31250<2^15)
  }
  __syncthreads();
  for (int j = t; j < kNumCells; j += 256) {
    u32 cnt = (h[j >> 1] >> ((j & 1u) * 16u)) & 0xFFFFu;
    hist[(size_t)j * kHistBlocks + b] = cnt;
  }
}

// ---------------- B: exclusive scan over hist [cell][block] ----------------
__global__ __launch_bounds__(256)
void scan_block_kernel(u32* __restrict__ data, u32* __restrict__ sums)
{
  __shared__ u32 s[256];
  int t = threadIdx.x;
  int base = blockIdx.x * 256;
  u32 v = data[base + t];
  s[t] = v;
  __syncthreads();
  #pragma unroll
  for (int off = 1; off < 256; off <<= 1) {
    u32 a = (t >= off) ? s[t - off] : 0u;
    __syncthreads();
    s[t] += a;
    __syncthreads();
  }
  if (t == 255) sums[blockIdx.x] = s[255];
  data[base + t] = s[t] - v;  // exclusive within block
}

__global__ __launch_bounds__(64)
void scan_small_kernel(u32* __restrict__ d, int m)
{
  if (threadIdx.x == 0) {
    u32 acc = 0;
    for (int j = 0; j < m; ++j) { u32 v = d[j]; d[j] = acc; acc += v; }
  }
}

__global__ __launch_bounds__(256)
void add_offsets_kernel(u32* __restrict__ data, const u32* __restrict__ sums)
{
  data[blockIdx.x * 256 + threadIdx.x] += sums[blockIdx.x];
}

// ---------------- C: full-grid scatter (no LDS, no atomics) ----------------
__global__ __launch_bounds__(256)
void scatter_kernel(const float* __restrict__ points, const float* __restrict__ aabb,
                    const u32* __restrict__ hist, const u32* __restrict__ cr,
                    float4* __restrict__ sp, int n, int ppb)
{
  int i = blockIdx.x * blockDim.x + threadIdx.x;
  if (i >= n) return;
  float a0x = aabb[0], a0y = aabb[1], a0z = aabb[2];
  float a1x = aabb[3], a1y = aabb[4], a1z = aabb[5];
  float x = fminf(fmaxf((points[3 * i + 0] - a0x) / (a1x - a0x), 0.f), 1.f);
  float y = fminf(fmaxf((points[3 * i + 1] - a0y) / (a1y - a0y), 0.f), 1.f);
  float z = fminf(fmaxf((points[3 * i + 2] - a0z) / (a1z - a0z), 0.f), 1.f);
  u32 v = cr[i];
  u32 c = v & 0x7FFFu;
  u32 rank = v >> 15;
  int b = i / ppb;
  u32 pos = hist[(size_t)c * kHistBlocks + b] + rank;
  sp[pos] = make_float4(x, y, z, __uint_as_float((u32)i));
}

// ---------------- encode (sorted coords), widened pair gathers ----------------
__device__ __forceinline__ u32 sel4(uint4 v, u32 j) {
  u32 lo = (j & 1u) ? v.y : v.x;
  u32 hi = (j & 1u) ? v.w : v.z;
  return (j & 2u) ? hi : lo;
}

__global__ __launch_bounds__(256)
void encode_sorted_kernel(const float4* __restrict__ sp,
                          const u32* __restrict__ tables,
                          half2_t* __restrict__ enc,   // [L][N]
                          LevelParams lp, int n, int bpl)
{
  int l = blockIdx.x / bpl;
  int i = (blockIdx.x - l * bpl) * blockDim.x + threadIdx.x;
  if (i >= n) return;

  float4 c = sp[i];
  float x = c.x, y = c.y, z = c.z;

  float s = lp.scale[l];
  unsigned res = lp.res[l];
  bool dense = (lp.dense[l] != 0);
  unsigned rm1 = res - 1u;
  unsigned res2 = res * res;
  const u32* tab = tables + (size_t)l * kTableSize;

  float fx = x * s + 0.5f, fy = y * s + 0.5f, fz = z * s + 0.5f;
  float fx0 = floorf(fx), fy0 = floorf(fy), fz0 = floorf(fz);
  float wx = fx - fx0, wy = fy - fy0, wz = fz - fz0;
  unsigned bx = (unsigned)fx0, by = (unsigned)fy0, bz = (unsigned)fz0;

  unsigned pcx0 = min(bx, rm1), pcx1 = min(bx + 1u, rm1);

  u32 idx0[4], idx1[4];
  #pragma unroll
  for (int p = 0; p < 4; ++p) {
    unsigned oy = (unsigned)(p & 1);
    unsigned oz = (unsigned)(p >> 1);
    unsigned pcy = min(by + oy, rm1);
    unsigned pcz = min(bz + oz, rm1);
    if (dense) {
      u32 bb = pcy * res + pcz * res2;
      idx0[p] = pcx0 + bb;
      idx1[p] = pcx1 + bb;
    } else {
      u32 h = (pcy * 2654435761u) ^ (pcz * 805459861u);
      idx0[p] = (pcx0 ^ h) & kMask;
      idx1[p] = (pcx1 ^ h) & kMask;
    }
  }

  uint4 v[4];
  #pragma unroll
  for (int p = 0; p < 4; ++p)
    v[p] = *reinterpret_cast<const uint4*>(tab + (idx0[p] & ~3u));

  u32 e1x[4] = {0u, 0u, 0u, 0u};
  #pragma unroll
  for (int p = 0; p < 4; ++p) {
    if ((idx0[p] ^ idx1[p]) >= 4u) e1x[p] = tab[idx1[p]];
  }

  float wx1 = wx, wx0 = 1.f - wx;
  float acc0 = 0.f, acc1 = 0.f;
  #pragma unroll
  for (int p = 0; p < 4; ++p) {
    unsigned oy = (unsigned)(p & 1);
    unsigned oz = (unsigned)(p >> 1);
    float wyz = (oy ? wy : 1.f - wy) * (oz ? wz : 1.f - wz);
    u32 e0 = sel4(v[p], idx0[p] & 3u);
    u32 e1g = sel4(v[p], idx1[p] & 3u);
    u32 e1 = ((idx0[p] ^ idx1[p]) < 4u) ? e1g : e1x[p];
    half2_t f0 = __builtin_bit_cast(half2_t, e0);
    half2_t f1 = __builtin_bit_cast(half2_t, e1);
    float w0 = wyz * wx0, w1 = wyz * wx1;
    acc0 += w0 * (float)f0.x + w1 * (float)f1.x;
    acc1 += w0 * (float)f0.y + w1 * (float)f1.y;
  }
  enc[(size_t)l * n + i] = half2_t{(_Float16)acc0, (_Float16)acc1};
}

// ---------------- MLP with fp16 dot2; scatter store via sp.w ----------------
__device__ __forceinline__ float dot2_acc(half2_t a, half2_t b, float c) {
#if __has_builtin(__builtin_amdgcn_fdot2)
  return __builtin_amdgcn_fdot2(a, b, c, false);
#else
  return c + (float)a.x * (float)b.x + (float)a.y * (float)b.y;
#endif
}

__global__ __launch_bounds__(256)
void mlp_kernel(const half2_t* __restrict__ enc,   // [L][N]
                const half2_t* __restrict__ Wh,    // [W1h 512 | W2h 512 | W3h 64]
                const float4* __restrict__ sp,     // nullable; .w = orig index
                float* __restrict__ out, int n)
{
  int i = blockIdx.x * blockDim.x + threadIdx.x;
  if (i >= n) return;

  half2_t e[16];
  #pragma unroll
  for (int l = 0; l < kLevels; ++l) e[l] = enc[(size_t)l * n + i];

  const half2_t* W1h = Wh;
  const half2_t* W2h = Wh + 512;
  const half2_t* W3h = Wh + 1024;

  float h1f[32];
  #pragma unroll
  for (int j = 0; j < 32; ++j) {
    float acc = 0.f;
    #pragma unroll
    for (int k = 0; k < 16; ++k) acc = dot2_acc(e[k], W1h[16 * j + k], acc);
    h1f[j] = fmaxf(acc, 0.f);
  }
  half2_t h1[16];
  #pragma unroll
  for (int k = 0; k < 16; ++k)
    h1[k] = half2_t{(_Float16)h1f[2 * k], (_Float16)h1f[2 * k + 1]};

  float h2f[32];
  #pragma unroll
  for (int j = 0; j < 32; ++j) {
    float acc = 0.f;
    #pragma unroll
    for (int k = 0; k < 16; ++k) acc = dot2_acc(h1[k], W2h[16 * j + k], acc);
    h2f[j] = fmaxf(acc, 0.f);
  }
  half2_t h2[16];
  #pragma unroll
  for (int k = 0; k < 16; ++k)
    h2[k] = half2_t{(_Float16)h2f[2 * k], (_Float16)h2f[2 * k + 1]};

  float o[4];
  #pragma unroll
  for (int j = 0; j < 4; ++j) {
    float acc = 0.f;
    #pragma unroll
    for (int k = 0; k < 16; ++k) acc = dot2_acc(h2[k], W3h[16 * j + k], acc);
    o[j] = acc;
  }

  float4 r;
  r.x = 1.f / (1.f + __expf(-o[0]));
  r.y = 1.f / (1.f + __expf(-o[1]));
  r.z = 1.f / (1.f + __expf(-o[2]));
  r.w = 0.99f / (1.f + __expf(-o[3])) + 0.01f;
  int oi = sp ? (int)__float_as_uint(sp[i].w) : i;
  reinterpret_cast<float4*>(out)[oi] = r;
}

// ---------------- encode on raw points (fallback, R3 path) ----------------
__global__ __launch_bounds__(256)
void encode_raw_kernel(const float* __restrict__ points,
                       const u32* __restrict__ tables,
                       const float* __restrict__ aabb,
                       half2_t* __restrict__ enc,
                       LevelParams lp, int n, int bpl)
{
  int l = blockIdx.x / bpl;
  int i = (blockIdx.x - l * bpl) * blockDim.x + threadIdx.x;
  if (i >= n) return;

  float a0x = aabb[0], a0y = aabb[1], a0z = aabb[2];
  float a1x = aabb[3], a1y = aabb[4], a1z = aabb[5];
  float x = fminf(fmaxf((points[3 * i + 0] - a0x) / (a1x - a0x), 0.f), 1.f);
  float y = fminf(fmaxf((points[3 * i + 1] - a0y) / (a1y - a0y), 0.f), 1.f);
  float z = fminf(fmaxf((points[3 * i + 2] - a0z) / (a1z - a0z), 0.f), 1.f);

  float s = lp.scale[l];
  unsigned res = lp.res[l];
  bool dense = (lp.dense[l] != 0);
  unsigned rm1 = res - 1u;
  unsigned res2 = res * res;
  const u32* tab = tables + (size_t)l * kTableSize;

  float fx = x * s + 0.5f, fy = y * s + 0.5f, fz = z * s + 0.5f;
  float fx0 = floorf(fx), fy0 = floorf(fy), fz0 = floorf(fz);
  float wx = fx - fx0, wy = fy - fy0, wz = fz - fz0;
  unsigned bx = (unsigned)fx0, by = (unsigned)fy0, bz = (unsigned)fz0;
  unsigned pcx0 = min(bx, rm1), pcx1 = min(bx + 1u, rm1);

  u32 idx0[4], idx1[4];
  #pragma unroll
  for (int p = 0; p < 4; ++p) {
    unsigned oy = (unsigned)(p & 1);
    unsigned oz = (unsigned)(p >> 1);
    unsigned pcy = min(by + oy, rm1);
    unsigned pcz = min(bz + oz, rm1);
    if (dense) {
      u32 bb = pcy * res + pcz * res2;
      idx0[p] = pcx0 + bb;
      idx1[p] = pcx1 + bb;
    } else {
      u32 h = (pcy * 2654435761u) ^ (pcz * 805459861u);
      idx0[p] = (pcx0 ^ h) & kMask;
      idx1[p] = (pcx1 ^ h) & kMask;
    }
  }
  uint4 v[4];
  #pragma unroll
  for (int p = 0; p < 4; ++p)
    v[p] = *reinterpret_cast<const uint4*>(tab + (idx0[p] & ~3u));
  u32 e1x[4] = {0u, 0u, 0u, 0u};
  #pragma unroll
  for (int p = 0; p < 4; ++p) {
    if ((idx0[p] ^ idx1[p]) >= 4u) e1x[p] = tab[idx1[p]];
  }
  float wx1 = wx, wx0 = 1.f - wx;
  float acc0 = 0.f, acc1 = 0.f;
  #pragma unroll
  for (int p = 0; p < 4; ++p) {
    unsigned oy = (unsigned)(p & 1);
    unsigned oz = (unsigned)(p >> 1);
    float wyz = (oy ? wy : 1.f - wy) * (oz ? wz : 1.f - wz);
    u32 e0 = sel4(v[p], idx0[p] & 3u);
    u32 e1g = sel4(v[p], idx1[p] & 3u);
    u32 e1 = ((idx0[p] ^ idx1[p]) < 4u) ? e1g : e1x[p];
    half2_t f0 = __builtin_bit_cast(half2_t, e0);
    half2_t f1 = __builtin_bit_cast(half2_t, e1);
    float w0 = wyz * wx0, w1 = wyz * wx1;
    acc0 += w0 * (float)f0.x + w1 * (float)f1.x;
    acc1 += w0 * (float)f0.y + w1 * (float)f1.y;
  }
  enc[(size_t)l * n + i] = half2_t{(_Float16)acc0, (_Float16)acc1};
}

// ---------------- last-resort fallback: R0 monolithic ----------------
__global__ __launch_bounds__(256)
void hashgrid_mlp_kernel(const float* __restrict__ points,
                         const float* __restrict__ tables,
                         const float* __restrict__ W1,
                         const float* __restrict__ W2,
                         const float* __restrict__ W3,
                         const float* __restrict__ aabb,
                         float* __restrict__ out,
                         LevelParams lp, int n)
{
  int i = blockIdx.x * blockDim.x + threadIdx.x;
  if (i >= n) return;
  float a0x = aabb[0], a0y = aabb[1], a0z = aabb[2];
  float a1x = aabb[3], a1y = aabb[4], a1z = aabb[5];
  float x = fminf(fmaxf((points[3 * i + 0] - a0x) / (a1x - a0x), 0.f), 1.f);
  float y = fminf(fmaxf((points[3 * i + 1] - a0y) / (a1y - a0y), 0.f), 1.f);
  float z = fminf(fmaxf((points[3 * i + 2] - a0z) / (a1z - a0z), 0.f), 1.f);
  float enc[2 * kLevels];
  #pragma unroll
  for (int l = 0; l < kLevels; ++l) {
    float s = lp.scale[l];
    unsigned res = lp.res[l];
    bool dense = (lp.dense[l] != 0);
    unsigned rm1 = res - 1u;
    unsigned res2 = res * res;
    float fx = x * s + 0.5f, fy = y * s + 0.5f, fz = z * s + 0.5f;
    float fx0 = floorf(fx), fy0 = floorf(fy), fz0 = floorf(fz);
    float wx = fx - fx0, wy = fy - fy0, wz = fz - fz0;
    unsigned bx = (unsigned)fx0, by = (unsigned)fy0, bz = (unsigned)fz0;
    const float2* tab = reinterpret_cast<const float2*>(tables) + (size_t)l * kTableSize;
    float acc0 = 0.f, acc1 = 0.f;
    #pragma unroll
    for (int c = 0; c < 8; ++c) {
      unsigned ox = (unsigned)(c & 1);
      unsigned oy = (unsigned)((c >> 1) & 1);
      unsigned oz = (unsigned)((c >> 2) & 1);
      unsigned pcx = min(bx + ox, rm1);
      unsigned pcy = min(by + oy, rm1);
      unsigned pcz = min(bz + oz, rm1);
      unsigned idx;
      if (dense) idx = pcx + pcy * res + pcz * res2;
      else idx = (pcx ^ (pcy * 2654435761u) ^ (pcz * 805459861u)) & kMask;
      float wt = (ox ? wx : 1.f - wx) * (oy ? wy : 1.f - wy) * (oz ? wz : 1.f - wz);
      float2 f = tab[idx];
      acc0 += wt * f.x;
      acc1 += wt * f.y;
    }
    enc[2 * l + 0] = acc0;
    enc[2 * l + 1] = acc1;
  }
  float h1[32];
  #pragma unroll
  for (int j = 0; j < 32; ++j) {
    float acc = 0.f;
    #pragma unroll
    for (int k = 0; k < 32; ++k) acc += enc[k] * W1[32 * j + k];
    h1[j] = fmaxf(acc, 0.f);
  }
  float h2[32];
  #pragma unroll
  for (int j = 0; j < 32; ++j) {
    float acc = 0.f;
    #pragma unroll
    for (int k = 0; k < 32; ++k) acc += h1[k] * W2[32 * j + k];
    h2[j] = fmaxf(acc, 0.f);
  }
  float o[4];
  #pragma unroll
  for (int j = 0; j < 4; ++j) {
    float acc = 0.f;
    #pragma unroll
    for (int k = 0; k < 32; ++k) acc += h2[k] * W3[32 * j + k];
    o[j] = acc;
  }
  float4 r;
  r.x = 1.f / (1.f + __expf(-o[0]));
  r.y = 1.f / (1.f + __expf(-o[1]));
  r.z = 1.f / (1.f + __expf(-o[2]));
  r.w = 0.99f / (1.f + __expf(-o[3])) + 0.01f;
  reinterpret_cast<float4*>(out)[i] = r;
}

extern "C" void kernel_launch(void* const* d_in, const int* in_sizes, int n_in,
                              void* d_out, int out_size, void* d_ws, size_t ws_size,
                              hipStream_t stream) {
  const float* points = (const float*)d_in[0];
  const float* tables = (const float*)d_in[1];
  const float* W1     = (const float*)d_in[2];
  const float* W2     = (const float*)d_in[3];
  const float* W3     = (const float*)d_in[4];
  const float* aabb   = (const float*)d_in[5];
  float* out = (float*)d_out;
  int n = in_sizes[0] / 3;

  LevelParams lp;
  const double pls = std::exp(std::log(4096.0 / 16.0) / 15.0);
  for (int l = 0; l < kLevels; ++l) {
    double s = 16.0 * std::pow(pls, (double)l) - 1.0;
    lp.scale[l] = (float)s;
    long long res = (long long)std::ceil(s) + 1;
    lp.res[l] = (unsigned)res;
    lp.dense[l] = (res * res * res <= (long long)kTableSize) ? 1 : 0;
  }

  const int block = 256;
  const int n_entries = kLevels * (int)kTableSize;
  const int grid_n = (n + block - 1) / block;
  const int ppb = (n + kHistBlocks - 1) / kHistBlocks;   // 31250 for n=2M (<2^15)

  auto align256 = [](size_t v) { return (v + 255) & ~(size_t)255; };
  const size_t tab_b   = align256((size_t)n_entries * 4);          // 32 MB
  const size_t enc_b   = align256((size_t)kLevels * n * 4);        // 128 MB
  const size_t wh_b    = align256(1088 * 4);
  const size_t sp_b    = align256((size_t)n * 16);                 // 32 MB
  // binning scratch aliases the enc region (binning completes before encode):
  const size_t cr_b    = align256((size_t)n * 4);                  // 8 MB
  const size_t hist_b  = align256((size_t)kHistEntries * 4);       // 8 MB
  const size_t sumA_b  = align256((size_t)kScan1Blocks * 4);       // 32 KB
  const size_t sumB_b  = align256((size_t)kScan2Blocks * 4);
  const size_t bin_need = cr_b + hist_b + sumA_b + sumB_b;         // < enc_b
  const size_t need_sorted = tab_b + enc_b + wh_b + sp_b;
  const size_t need_r3     = tab_b + enc_b + wh_b;

  if (ws_size >= need_sorted && bin_need <= enc_b && ppb < (1 << 15)) {
    char* p = (char*)d_ws;
    half2_t* tab_f16 = (half2_t*)p;            p += tab_b;
    char*    enc_rgn = p;                      p += enc_b;
    half2_t* Wh      = (half2_t*)p;            p += wh_b;
    float4*  sp      = (float4*)p;

    half2_t* enc = (half2_t*)enc_rgn;
    // aliased binning scratch (dead once encode starts writing enc):
    u32* cr   = (u32*)enc_rgn;
    u32* hist = (u32*)(enc_rgn + cr_b);
    u32* sumA = (u32*)(enc_rgn + cr_b + hist_b);
    u32* sumB = (u32*)(enc_rgn + cr_b + hist_b + sumA_b);

    conv_tables_kernel<<<4096, block, 0, stream>>>(
        reinterpret_cast<const float2*>(tables), tab_f16, n_entries, W1, W2, W3, Wh);

    hist_pack_kernel<<<kHistBlocks, block, 0, stream>>>(points, aabb, hist, cr, n, ppb);
    scan_block_kernel<<<kScan1Blocks, 256, 0, stream>>>(hist, sumA);
    scan_block_kernel<<<kScan2Blocks, 256, 0, stream>>>(sumA, sumB);
    scan_small_kernel<<<1, 64, 0, stream>>>(sumB, kScan2Blocks);
    add_offsets_kernel<<<kScan2Blocks, 256, 0, stream>>>(sumA, sumB);
    add_offsets_kernel<<<kScan1Blocks, 256, 0, stream>>>(hist, sumA);
    scatter_kernel<<<grid_n, block, 0, stream>>>(points, aabb, hist, cr, sp, n, ppb);

    encode_sorted_kernel<<<grid_n * kLevels, block, 0, stream>>>(
        sp, reinterpret_cast<const u32*>(tab_f16), enc, lp, n, grid_n);

    mlp_kernel<<<grid_n, block, 0, stream>>>(enc, Wh, sp, out, n);
  } else if (ws_size >= need_r3) {
    char* p = (char*)d_ws;
    half2_t* tab_f16 = (half2_t*)p;            p += tab_b;
    half2_t* enc     = (half2_t*)p;            p += enc_b;
    half2_t* Wh      = (half2_t*)p;

    conv_tables_kernel<<<4096, block, 0, stream>>>(
        reinterpret_cast<const float2*>(tables), tab_f16, n_entries, W1, W2, W3, Wh);
    encode_raw_kernel<<<grid_n * kLevels, block, 0, stream>>>(
        points, reinterpret_cast<const u32*>(tab_f16), aabb, enc, lp, n, grid_n);
    mlp_kernel<<<grid_n, block, 0, stream>>>(enc, Wh, nullptr, out, n);
  } else {
    hashgrid_mlp_kernel<<<grid_n, block, 0, stream>>>(
        points, tables, W1, W2, W3, aabb, out, lp, n);
  }
}

// Round 9
// 830.379 us; speedup vs baseline: 1.0558x; 1.0558x over previous
//
#include <hip/hip_runtime.h>
#include <cmath>

// MLPTexture3D: 16-level hashgrid encode + 32->32->32->4 MLP.
// R8: full-occupancy counting sort. 512 hist blocks (2/CU @ 64KB LDS), matrix
// [block][cell] so all matrix traffic is coalesced; column scan done chunked
// (colsum4 -> scan32K -> base -> colscan4), all full-grid. Rank packed with
// cell in one u32 per point during hist (LDS dual-u16 atomicAdd-return).
// Encode level-phased on sorted coords (406us, FETCH 351MB); MLP scatters out.

namespace {
constexpr int kLevels = 16;
constexpr unsigned kTableSize = 1u << 19;
constexpr unsigned kMask = kTableSize - 1u;
constexpr int kNumCells = 1 << 15;        // 32^3 Morton cells
constexpr int kHistBlocks = 512;          // 4 chunks x 128 rows
constexpr int kChunkRows = 128;
constexpr int kHistEntries = kNumCells * kHistBlocks;  // 16M (64 MB)

typedef _Float16 half2_t __attribute__((ext_vector_type(2)));
typedef unsigned int u32;

struct LevelParams {
  float scale[kLevels];
  unsigned res[kLevels];
  int dense[kLevels];
};
}  // namespace

__device__ __forceinline__ u32 part1by2(u32 x) {
  x &= 0x3FFu;
  x = (x | (x << 16)) & 0x030000FFu;
  x = (x | (x << 8))  & 0x0300F00Fu;
  x = (x | (x << 4))  & 0x030C30C3u;
  x = (x | (x << 2))  & 0x09249249u;
  return x;
}

__device__ __forceinline__ u32 cell_of(float x, float y, float z) {
  u32 cx = min((u32)(x * 32.f), 31u);
  u32 cy = min((u32)(y * 32.f), 31u);
  u32 cz = min((u32)(z * 32.f), 31u);
  return part1by2(cx) | (part1by2(cy) << 1) | (part1by2(cz) << 2);
}

// ---------------- k0: table conversion + weight packing ----------------
__global__ __launch_bounds__(256)
void conv_tables_kernel(const float2* __restrict__ src, half2_t* __restrict__ dst,
                        int n_entries,
                        const float* __restrict__ W1, const float* __restrict__ W2,
                        const float* __restrict__ W3, half2_t* __restrict__ Wh)
{
  int i = blockIdx.x * blockDim.x + threadIdx.x;
  if (i < 512) {
    Wh[i] = half2_t{(_Float16)W1[2 * i], (_Float16)W1[2 * i + 1]};
  } else if (i < 1024) {
    int t = i - 512;
    Wh[512 + t] = half2_t{(_Float16)W2[2 * t], (_Float16)W2[2 * t + 1]};
  } else if (i < 1088) {
    int t = i - 1024;
    Wh[1024 + t] = half2_t{(_Float16)W3[2 * t], (_Float16)W3[2 * t + 1]};
  }
  int stride = gridDim.x * blockDim.x;
  for (; i < n_entries; i += stride) {
    float2 v = src[i];
    dst[i] = half2_t{(_Float16)v.x, (_Float16)v.y};
  }
}

// ---------------- A: hist + per-point (cell,rank) in one pass ----------------
// LDS: 32768 cells as dual u16 counters packed in 16384 u32 (64 KB).
__global__ __launch_bounds__(256)
void hist_pack_kernel(const float* __restrict__ points, const float* __restrict__ aabb,
                      u32* __restrict__ hist, u32* __restrict__ cr, int n, int ppb)
{
  __shared__ u32 h[kNumCells / 2];
  int t = threadIdx.x;
  int b = blockIdx.x;
  for (int j = t; j < kNumCells / 2; j += 256) h[j] = 0u;
  __syncthreads();

  float a0x = aabb[0], a0y = aabb[1], a0z = aabb[2];
  float a1x = aabb[3], a1y = aabb[4], a1z = aabb[5];
  int start = b * ppb;
  int end = min(start + ppb, n);
  for (int i = start + t; i < end; i += 256) {
    float x = fminf(fmaxf((points[3 * i + 0] - a0x) / (a1x - a0x), 0.f), 1.f);
    float y = fminf(fmaxf((points[3 * i + 1] - a0y) / (a1y - a0y), 0.f), 1.f);
    float z = fminf(fmaxf((points[3 * i + 2] - a0z) / (a1z - a0z), 0.f), 1.f);
    u32 c = cell_of(x, y, z);
    u32 sh = (c & 1u) * 16u;
    u32 old = atomicAdd(&h[c >> 1], 1u << sh);
    u32 rank = (old >> sh) & 0xFFFFu;
    cr[i] = c | (rank << 15);   // cell 15b | rank (ppb=3907 < 2^12)
  }
  __syncthreads();
  // coalesced row write: hist[b][c]
  u32* row = hist + (size_t)b * kNumCells;
  for (int j = t; j < kNumCells; j += 256) {
    u32 cnt = (h[j >> 1] >> ((j & 1u) * 16u)) & 0xFFFFu;
    row[j] = cnt;
  }
}

// ---------------- B: chunked column reduction / scan ----------------
// partial[chunk][c] = sum of hist[b][c] over the chunk's 128 rows
__global__ __launch_bounds__(256)
void colsum4_kernel(const u32* __restrict__ hist, u32* __restrict__ partial)
{
  int chunk = blockIdx.x >> 7;
  int c = (blockIdx.x & 127) * 256 + threadIdx.x;
  const u32* row = hist + (size_t)chunk * kChunkRows * kNumCells + c;
  u32 acc = 0;
  #pragma unroll 4
  for (int b = 0; b < kChunkRows; ++b) acc += row[(size_t)b * kNumCells];
  partial[chunk * kNumCells + c] = acc;
}

__global__ __launch_bounds__(256)
void combine_kernel(const u32* __restrict__ partial, u32* __restrict__ colsum)
{
  int c = blockIdx.x * 256 + threadIdx.x;
  colsum[c] = partial[c] + partial[kNumCells + c] +
              partial[2 * kNumCells + c] + partial[3 * kNumCells + c];
}

__global__ __launch_bounds__(256)
void scan_block_kernel(u32* __restrict__ data, u32* __restrict__ sums)
{
  __shared__ u32 s[256];
  int t = threadIdx.x;
  int base = blockIdx.x * 256;
  u32 v = data[base + t];
  s[t] = v;
  __syncthreads();
  #pragma unroll
  for (int off = 1; off < 256; off <<= 1) {
    u32 a = (t >= off) ? s[t - off] : 0u;
    __syncthreads();
    s[t] += a;
    __syncthreads();
  }
  if (t == 255) sums[blockIdx.x] = s[255];
  data[base + t] = s[t] - v;  // exclusive within block
}

__global__ __launch_bounds__(64)
void scan_small_kernel(u32* __restrict__ d, int m)
{
  if (threadIdx.x == 0) {
    u32 acc = 0;
    for (int j = 0; j < m; ++j) { u32 v = d[j]; d[j] = acc; acc += v; }
  }
}

__global__ __launch_bounds__(256)
void add_offsets_kernel(u32* __restrict__ data, const u32* __restrict__ sums)
{
  data[blockIdx.x * 256 + threadIdx.x] += sums[blockIdx.x];
}

// partial[chunk][c] <- colsum[c] + exclusive-sum of partials over chunks
__global__ __launch_bounds__(256)
void base_kernel(u32* __restrict__ partial, const u32* __restrict__ colsum)
{
  int c = blockIdx.x * 256 + threadIdx.x;
  u32 p0 = partial[c];
  u32 p1 = partial[kNumCells + c];
  u32 p2 = partial[2 * kNumCells + c];
  u32 b0 = colsum[c];
  partial[c] = b0;
  partial[kNumCells + c] = b0 + p0;
  partial[2 * kNumCells + c] = b0 + p0 + p1;
  partial[3 * kNumCells + c] = b0 + p0 + p1 + p2;
}

// column-wise exclusive scan within each chunk: hist[b][c] <- global offset
__global__ __launch_bounds__(256)
void colscan4_kernel(u32* __restrict__ hist, const u32* __restrict__ partial)
{
  int chunk = blockIdx.x >> 7;
  int c = (blockIdx.x & 127) * 256 + threadIdx.x;
  u32 acc = partial[chunk * kNumCells + c];
  u32* row = hist + (size_t)chunk * kChunkRows * kNumCells + c;
  for (int b = 0; b < kChunkRows; ++b) {
    u32 v = row[(size_t)b * kNumCells];
    row[(size_t)b * kNumCells] = acc;
    acc += v;
  }
}

// ---------------- C: full-grid scatter (no LDS, no atomics) ----------------
__global__ __launch_bounds__(256)
void scatter_kernel(const float* __restrict__ points, const float* __restrict__ aabb,
                    const u32* __restrict__ hist, const u32* __restrict__ cr,
                    float4* __restrict__ sp, int n, int ppb)
{
  int i = blockIdx.x * blockDim.x + threadIdx.x;
  if (i >= n) return;
  float a0x = aabb[0], a0y = aabb[1], a0z = aabb[2];
  float a1x = aabb[3], a1y = aabb[4], a1z = aabb[5];
  float x = fminf(fmaxf((points[3 * i + 0] - a0x) / (a1x - a0x), 0.f), 1.f);
  float y = fminf(fmaxf((points[3 * i + 1] - a0y) / (a1y - a0y), 0.f), 1.f);
  float z = fminf(fmaxf((points[3 * i + 2] - a0z) / (a1z - a0z), 0.f), 1.f);
  u32 v = cr[i];
  u32 c = v & 0x7FFFu;
  u32 rank = v >> 15;
  int b = i / ppb;
  u32 pos = hist[(size_t)b * kNumCells + c] + rank;  // row b is L2-hot (128 KB)
  sp[pos] = make_float4(x, y, z, __uint_as_float((u32)i));
}

// ---------------- encode (sorted coords), widened pair gathers ----------------
__device__ __forceinline__ u32 sel4(uint4 v, u32 j) {
  u32 lo = (j & 1u) ? v.y : v.x;
  u32 hi = (j & 1u) ? v.w : v.z;
  return (j & 2u) ? hi : lo;
}

__global__ __launch_bounds__(256)
void encode_sorted_kernel(const float4* __restrict__ sp,
                          const u32* __restrict__ tables,
                          half2_t* __restrict__ enc,   // [L][N]
                          LevelParams lp, int n, int bpl)
{
  int l = blockIdx.x / bpl;
  int i = (blockIdx.x - l * bpl) * blockDim.x + threadIdx.x;
  if (i >= n) return;

  float4 c = sp[i];
  float x = c.x, y = c.y, z = c.z;

  float s = lp.scale[l];
  unsigned res = lp.res[l];
  bool dense = (lp.dense[l] != 0);
  unsigned rm1 = res - 1u;
  unsigned res2 = res * res;
  const u32* tab = tables + (size_t)l * kTableSize;

  float fx = x * s + 0.5f, fy = y * s + 0.5f, fz = z * s + 0.5f;
  float fx0 = floorf(fx), fy0 = floorf(fy), fz0 = floorf(fz);
  float wx = fx - fx0, wy = fy - fy0, wz = fz - fz0;
  unsigned bx = (unsigned)fx0, by = (unsigned)fy0, bz = (unsigned)fz0;

  unsigned pcx0 = min(bx, rm1), pcx1 = min(bx + 1u, rm1);

  u32 idx0[4], idx1[4];
  #pragma unroll
  for (int p = 0; p < 4; ++p) {
    unsigned oy = (unsigned)(p & 1);
    unsigned oz = (unsigned)(p >> 1);
    unsigned pcy = min(by + oy, rm1);
    unsigned pcz = min(bz + oz, rm1);
    if (dense) {
      u32 bb = pcy * res + pcz * res2;
      idx0[p] = pcx0 + bb;
      idx1[p] = pcx1 + bb;
    } else {
      u32 h = (pcy * 2654435761u) ^ (pcz * 805459861u);
      idx0[p] = (pcx0 ^ h) & kMask;
      idx1[p] = (pcx1 ^ h) & kMask;
    }
  }

  uint4 v[4];
  #pragma unroll
  for (int p = 0; p < 4; ++p)
    v[p] = *reinterpret_cast<const uint4*>(tab + (idx0[p] & ~3u));

  u32 e1x[4] = {0u, 0u, 0u, 0u};
  #pragma unroll
  for (int p = 0; p < 4; ++p) {
    if ((idx0[p] ^ idx1[p]) >= 4u) e1x[p] = tab[idx1[p]];
  }

  float wx1 = wx, wx0 = 1.f - wx;
  float acc0 = 0.f, acc1 = 0.f;
  #pragma unroll
  for (int p = 0; p < 4; ++p) {
    unsigned oy = (unsigned)(p & 1);
    unsigned oz = (unsigned)(p >> 1);
    float wyz = (oy ? wy : 1.f - wy) * (oz ? wz : 1.f - wz);
    u32 e0 = sel4(v[p], idx0[p] & 3u);
    u32 e1g = sel4(v[p], idx1[p] & 3u);
    u32 e1 = ((idx0[p] ^ idx1[p]) < 4u) ? e1g : e1x[p];
    half2_t f0 = __builtin_bit_cast(half2_t, e0);
    half2_t f1 = __builtin_bit_cast(half2_t, e1);
    float w0 = wyz * wx0, w1 = wyz * wx1;
    acc0 += w0 * (float)f0.x + w1 * (float)f1.x;
    acc1 += w0 * (float)f0.y + w1 * (float)f1.y;
  }
  enc[(size_t)l * n + i] = half2_t{(_Float16)acc0, (_Float16)acc1};
}

// ---------------- MLP with fp16 dot2; scatter store via sp.w ----------------
__device__ __forceinline__ float dot2_acc(half2_t a, half2_t b, float c) {
#if __has_builtin(__builtin_amdgcn_fdot2)
  return __builtin_amdgcn_fdot2(a, b, c, false);
#else
  return c + (float)a.x * (float)b.x + (float)a.y * (float)b.y;
#endif
}

__global__ __launch_bounds__(256)
void mlp_kernel(const half2_t* __restrict__ enc,   // [L][N]
                const half2_t* __restrict__ Wh,    // [W1h 512 | W2h 512 | W3h 64]
                const float4* __restrict__ sp,     // nullable; .w = orig index
                float* __restrict__ out, int n)
{
  int i = blockIdx.x * blockDim.x + threadIdx.x;
  if (i >= n) return;

  half2_t e[16];
  #pragma unroll
  for (int l = 0; l < kLevels; ++l) e[l] = enc[(size_t)l * n + i];

  const half2_t* W1h = Wh;
  const half2_t* W2h = Wh + 512;
  const half2_t* W3h = Wh + 1024;

  float h1f[32];
  #pragma unroll
  for (int j = 0; j < 32; ++j) {
    float acc = 0.f;
    #pragma unroll
    for (int k = 0; k < 16; ++k) acc = dot2_acc(e[k], W1h[16 * j + k], acc);
    h1f[j] = fmaxf(acc, 0.f);
  }
  half2_t h1[16];
  #pragma unroll
  for (int k = 0; k < 16; ++k)
    h1[k] = half2_t{(_Float16)h1f[2 * k], (_Float16)h1f[2 * k + 1]};

  float h2f[32];
  #pragma unroll
  for (int j = 0; j < 32; ++j) {
    float acc = 0.f;
    #pragma unroll
    for (int k = 0; k < 16; ++k) acc = dot2_acc(h1[k], W2h[16 * j + k], acc);
    h2f[j] = fmaxf(acc, 0.f);
  }
  half2_t h2[16];
  #pragma unroll
  for (int k = 0; k < 16; ++k)
    h2[k] = half2_t{(_Float16)h2f[2 * k], (_Float16)h2f[2 * k + 1]};

  float o[4];
  #pragma unroll
  for (int j = 0; j < 4; ++j) {
    float acc = 0.f;
    #pragma unroll
    for (int k = 0; k < 16; ++k) acc = dot2_acc(h2[k], W3h[16 * j + k], acc);
    o[j] = acc;
  }

  float4 r;
  r.x = 1.f / (1.f + __expf(-o[0]));
  r.y = 1.f / (1.f + __expf(-o[1]));
  r.z = 1.f / (1.f + __expf(-o[2]));
  r.w = 0.99f / (1.f + __expf(-o[3])) + 0.01f;
  int oi = sp ? (int)__float_as_uint(sp[i].w) : i;
  reinterpret_cast<float4*>(out)[oi] = r;
}

// ---------------- encode on raw points (fallback, R3 path) ----------------
__global__ __launch_bounds__(256)
void encode_raw_kernel(const float* __restrict__ points,
                       const u32* __restrict__ tables,
                       const float* __restrict__ aabb,
                       half2_t* __restrict__ enc,
                       LevelParams lp, int n, int bpl)
{
  int l = blockIdx.x / bpl;
  int i = (blockIdx.x - l * bpl) * blockDim.x + threadIdx.x;
  if (i >= n) return;

  float a0x = aabb[0], a0y = aabb[1], a0z = aabb[2];
  float a1x = aabb[3], a1y = aabb[4], a1z = aabb[5];
  float x = fminf(fmaxf((points[3 * i + 0] - a0x) / (a1x - a0x), 0.f), 1.f);
  float y = fminf(fmaxf((points[3 * i + 1] - a0y) / (a1y - a0y), 0.f), 1.f);
  float z = fminf(fmaxf((points[3 * i + 2] - a0z) / (a1z - a0z), 0.f), 1.f);

  float s = lp.scale[l];
  unsigned res = lp.res[l];
  bool dense = (lp.dense[l] != 0);
  unsigned rm1 = res - 1u;
  unsigned res2 = res * res;
  const u32* tab = tables + (size_t)l * kTableSize;

  float fx = x * s + 0.5f, fy = y * s + 0.5f, fz = z * s + 0.5f;
  float fx0 = floorf(fx), fy0 = floorf(fy), fz0 = floorf(fz);
  float wx = fx - fx0, wy = fy - fy0, wz = fz - fz0;
  unsigned bx = (unsigned)fx0, by = (unsigned)fy0, bz = (unsigned)fz0;
  unsigned pcx0 = min(bx, rm1), pcx1 = min(bx + 1u, rm1);

  u32 idx0[4], idx1[4];
  #pragma unroll
  for (int p = 0; p < 4; ++p) {
    unsigned oy = (unsigned)(p & 1);
    unsigned oz = (unsigned)(p >> 1);
    unsigned pcy = min(by + oy, rm1);
    unsigned pcz = min(bz + oz, rm1);
    if (dense) {
      u32 bb = pcy * res + pcz * res2;
      idx0[p] = pcx0 + bb;
      idx1[p] = pcx1 + bb;
    } else {
      u32 h = (pcy * 2654435761u) ^ (pcz * 805459861u);
      idx0[p] = (pcx0 ^ h) & kMask;
      idx1[p] = (pcx1 ^ h) & kMask;
    }
  }
  uint4 v[4];
  #pragma unroll
  for (int p = 0; p < 4; ++p)
    v[p] = *reinterpret_cast<const uint4*>(tab + (idx0[p] & ~3u));
  u32 e1x[4] = {0u, 0u, 0u, 0u};
  #pragma unroll
  for (int p = 0; p < 4; ++p) {
    if ((idx0[p] ^ idx1[p]) >= 4u) e1x[p] = tab[idx1[p]];
  }
  float wx1 = wx, wx0 = 1.f - wx;
  float acc0 = 0.f, acc1 = 0.f;
  #pragma unroll
  for (int p = 0; p < 4; ++p) {
    unsigned oy = (unsigned)(p & 1);
    unsigned oz = (unsigned)(p >> 1);
    float wyz = (oy ? wy : 1.f - wy) * (oz ? wz : 1.f - wz);
    u32 e0 = sel4(v[p], idx0[p] & 3u);
    u32 e1g = sel4(v[p], idx1[p] & 3u);
    u32 e1 = ((idx0[p] ^ idx1[p]) < 4u) ? e1g : e1x[p];
    half2_t f0 = __builtin_bit_cast(half2_t, e0);
    half2_t f1 = __builtin_bit_cast(half2_t, e1);
    float w0 = wyz * wx0, w1 = wyz * wx1;
    acc0 += w0 * (float)f0.x + w1 * (float)f1.x;
    acc1 += w0 * (float)f0.y + w1 * (float)f1.y;
  }
  enc[(size_t)l * n + i] = half2_t{(_Float16)acc0, (_Float16)acc1};
}

// ---------------- last-resort fallback: R0 monolithic ----------------
__global__ __launch_bounds__(256)
void hashgrid_mlp_kernel(const float* __restrict__ points,
                         const float* __restrict__ tables,
                         const float* __restrict__ W1,
                         const float* __restrict__ W2,
                         const float* __restrict__ W3,
                         const float* __restrict__ aabb,
                         float* __restrict__ out,
                         LevelParams lp, int n)
{
  int i = blockIdx.x * blockDim.x + threadIdx.x;
  if (i >= n) return;
  float a0x = aabb[0], a0y = aabb[1], a0z = aabb[2];
  float a1x = aabb[3], a1y = aabb[4], a1z = aabb[5];
  float x = fminf(fmaxf((points[3 * i + 0] - a0x) / (a1x - a0x), 0.f), 1.f);
  float y = fminf(fmaxf((points[3 * i + 1] - a0y) / (a1y - a0y), 0.f), 1.f);
  float z = fminf(fmaxf((points[3 * i + 2] - a0z) / (a1z - a0z), 0.f), 1.f);
  float enc[2 * kLevels];
  #pragma unroll
  for (int l = 0; l < kLevels; ++l) {
    float s = lp.scale[l];
    unsigned res = lp.res[l];
    bool dense = (lp.dense[l] != 0);
    unsigned rm1 = res - 1u;
    unsigned res2 = res * res;
    float fx = x * s + 0.5f, fy = y * s + 0.5f, fz = z * s + 0.5f;
    float fx0 = floorf(fx), fy0 = floorf(fy), fz0 = floorf(fz);
    float wx = fx - fx0, wy = fy - fy0, wz = fz - fz0;
    unsigned bx = (unsigned)fx0, by = (unsigned)fy0, bz = (unsigned)fz0;
    const float2* tab = reinterpret_cast<const float2*>(tables) + (size_t)l * kTableSize;
    float acc0 = 0.f, acc1 = 0.f;
    #pragma unroll
    for (int c = 0; c < 8; ++c) {
      unsigned ox = (unsigned)(c & 1);
      unsigned oy = (unsigned)((c >> 1) & 1);
      unsigned oz = (unsigned)((c >> 2) & 1);
      unsigned pcx = min(bx + ox, rm1);
      unsigned pcy = min(by + oy, rm1);
      unsigned pcz = min(bz + oz, rm1);
      unsigned idx;
      if (dense) idx = pcx + pcy * res + pcz * res2;
      else idx = (pcx ^ (pcy * 2654435761u) ^ (pcz * 805459861u)) & kMask;
      float wt = (ox ? wx : 1.f - wx) * (oy ? wy : 1.f - wy) * (oz ? wz : 1.f - wz);
      float2 f = tab[idx];
      acc0 += wt * f.x;
      acc1 += wt * f.y;
    }
    enc[2 * l + 0] = acc0;
    enc[2 * l + 1] = acc1;
  }
  float h1[32];
  #pragma unroll
  for (int j = 0; j < 32; ++j) {
    float acc = 0.f;
    #pragma unroll
    for (int k = 0; k < 32; ++k) acc += enc[k] * W1[32 * j + k];
    h1[j] = fmaxf(acc, 0.f);
  }
  float h2[32];
  #pragma unroll
  for (int j = 0; j < 32; ++j) {
    float acc = 0.f;
    #pragma unroll
    for (int k = 0; k < 32; ++k) acc += h1[k] * W2[32 * j + k];
    h2[j] = fmaxf(acc, 0.f);
  }
  float o[4];
  #pragma unroll
  for (int j = 0; j < 4; ++j) {
    float acc = 0.f;
    #pragma unroll
    for (int k = 0; k < 32; ++k) acc += h2[k] * W3[32 * j + k];
    o[j] = acc;
  }
  float4 r;
  r.x = 1.f / (1.f + __expf(-o[0]));
  r.y = 1.f / (1.f + __expf(-o[1]));
  r.z = 1.f / (1.f + __expf(-o[2]));
  r.w = 0.99f / (1.f + __expf(-o[3])) + 0.01f;
  reinterpret_cast<float4*>(out)[i] = r;
}

extern "C" void kernel_launch(void* const* d_in, const int* in_sizes, int n_in,
                              void* d_out, int out_size, void* d_ws, size_t ws_size,
                              hipStream_t stream) {
  const float* points = (const float*)d_in[0];
  const float* tables = (const float*)d_in[1];
  const float* W1     = (const float*)d_in[2];
  const float* W2     = (const float*)d_in[3];
  const float* W3     = (const float*)d_in[4];
  const float* aabb   = (const float*)d_in[5];
  float* out = (float*)d_out;
  int n = in_sizes[0] / 3;

  LevelParams lp;
  const double pls = std::exp(std::log(4096.0 / 16.0) / 15.0);
  for (int l = 0; l < kLevels; ++l) {
    double s = 16.0 * std::pow(pls, (double)l) - 1.0;
    lp.scale[l] = (float)s;
    long long res = (long long)std::ceil(s) + 1;
    lp.res[l] = (unsigned)res;
    lp.dense[l] = (res * res * res <= (long long)kTableSize) ? 1 : 0;
  }

  const int block = 256;
  const int n_entries = kLevels * (int)kTableSize;
  const int grid_n = (n + block - 1) / block;
  const int ppb = (n + kHistBlocks - 1) / kHistBlocks;   // 3907 for n=2M

  auto align256 = [](size_t v) { return (v + 255) & ~(size_t)255; };
  const size_t tab_b   = align256((size_t)n_entries * 4);          // 32 MB
  const size_t enc_b   = align256((size_t)kLevels * n * 4);        // 128 MB
  const size_t wh_b    = align256(1088 * 4);
  const size_t sp_b    = align256((size_t)n * 16);                 // 32 MB
  // binning scratch aliases the enc region (binning completes before encode):
  const size_t cr_b    = align256((size_t)n * 4);                  // 8 MB
  const size_t hist_b  = align256((size_t)kHistEntries * 4);       // 64 MB
  const size_t part_b  = align256((size_t)4 * kNumCells * 4);      // 512 KB
  const size_t col_b   = align256((size_t)kNumCells * 4);          // 128 KB
  const size_t sum_b   = align256((size_t)(kNumCells / 256) * 4);  // 512 B
  const size_t bin_need = cr_b + hist_b + part_b + col_b + sum_b;  // ~72.7 MB
  const size_t need_sorted = tab_b + enc_b + wh_b + sp_b;
  const size_t need_r3     = tab_b + enc_b + wh_b;

  if (ws_size >= need_sorted && bin_need <= enc_b && ppb < (1 << 12)) {
    char* p = (char*)d_ws;
    half2_t* tab_f16 = (half2_t*)p;            p += tab_b;
    char*    enc_rgn = p;                      p += enc_b;
    half2_t* Wh      = (half2_t*)p;            p += wh_b;
    float4*  sp      = (float4*)p;

    half2_t* enc = (half2_t*)enc_rgn;
    // aliased binning scratch (dead once encode starts writing enc):
    u32* cr      = (u32*)enc_rgn;
    u32* hist    = (u32*)(enc_rgn + cr_b);
    u32* partial = (u32*)(enc_rgn + cr_b + hist_b);
    u32* colsum  = (u32*)(enc_rgn + cr_b + hist_b + part_b);
    u32* sums    = (u32*)(enc_rgn + cr_b + hist_b + part_b + col_b);

    conv_tables_kernel<<<4096, block, 0, stream>>>(
        reinterpret_cast<const float2*>(tables), tab_f16, n_entries, W1, W2, W3, Wh);

    hist_pack_kernel<<<kHistBlocks, block, 0, stream>>>(points, aabb, hist, cr, n, ppb);
    colsum4_kernel<<<512, block, 0, stream>>>(hist, partial);
    combine_kernel<<<kNumCells / 256, block, 0, stream>>>(partial, colsum);
    scan_block_kernel<<<kNumCells / 256, block, 0, stream>>>(colsum, sums);
    scan_small_kernel<<<1, 64, 0, stream>>>(sums, kNumCells / 256);
    add_offsets_kernel<<<kNumCells / 256, block, 0, stream>>>(colsum, sums);
    base_kernel<<<kNumCells / 256, block, 0, stream>>>(partial, colsum);
    colscan4_kernel<<<512, block, 0, stream>>>(hist, partial);
    scatter_kernel<<<grid_n, block, 0, stream>>>(points, aabb, hist, cr, sp, n, ppb);

    encode_sorted_kernel<<<grid_n * kLevels, block, 0, stream>>>(
        sp, reinterpret_cast<const u32*>(tab_f16), enc, lp, n, grid_n);

    mlp_kernel<<<grid_n, block, 0, stream>>>(enc, Wh, sp, out, n);
  } else if (ws_size >= need_r3) {
    char* p = (char*)d_ws;
    half2_t* tab_f16 = (half2_t*)p;            p += tab_b;
    half2_t* enc     = (half2_t*)p;            p += enc_b;
    half2_t* Wh      = (half2_t*)p;

    conv_tables_kernel<<<4096, block, 0, stream>>>(
        reinterpret_cast<const float2*>(tables), tab_f16, n_entries, W1, W2, W3, Wh);
    encode_raw_kernel<<<grid_n * kLevels, block, 0, stream>>>(
        points, reinterpret_cast<const u32*>(tab_f16), aabb, enc, lp, n, grid_n);
    mlp_kernel<<<grid_n, block, 0, stream>>>(enc, Wh, nullptr, out, n);
  } else {
    hashgrid_mlp_kernel<<<grid_n, block, 0, stream>>>(
        points, tables, W1, W2, W3, aabb, out, lp, n);
  }
}